// Round 1
// baseline (169.954 us; speedup 1.0000x reference)
//
#include <hip/hip_runtime.h>

// GraphProjection on MI355X.
// x:(8,512,64,64) f32, anchor/sigma:(128,512) f32.
// Outputs (concat): nodes (8,512,128) then soft_assign (8,128,256).
//
// Kernel 1: wg per (b, g, half-block). Stages 32-pixel chunks of x in LDS,
//   computes logits+softmax (pass 1) and S1[k] = sum_p x*soft (pass 2),
//   emits soft_assign directly, atomically accumulates node partials
//   (rs*S1 - ars*S0) and softsums into workspace.
// Kernel 2: finalize: /(softsum+1e-9), L2-normalize over C, transposed store.

#define NCH 512
#define CHUNK_STRIDE 522   // 522 mod 32 = 10 -> <=2-way LDS bank aliasing

struct SharedK1 {
  float rs [NCH * 8];            // [c][k] : 1/sigma
  float ars[NCH * 8];            // [c][k] : anchor/sigma
  float chunk[32 * CHUNK_STRIDE];// [p][c] staged x chunk (2 rows x 16 px)
  float soft[32 * 8];            // [p][k]
  float ssum[8];                 // running softsum for this half
};

__global__ __launch_bounds__(512, 2)
void gp_main(const float* __restrict__ x,
             const float* __restrict__ anchor,
             const float* __restrict__ sigma,
             float* __restrict__ soft_out,   // d_out + 524288
             float* __restrict__ ws_nodes,   // [128][8][512]
             float* __restrict__ ws_ssum) {  // [128][8]
  __shared__ SharedK1 sh;
  const int tid = threadIdx.x;
  const int bid = blockIdx.x;
  const int hh  = bid & 1;          // which half of the block (8 rows)
  const int g   = (bid >> 1) & 15;  // spatial block
  const int b   = bid >> 5;         // batch

  // ---- anchors -> LDS as [c][k]
  {
    const float* ab = anchor + g * 4096;
    const float* sb = sigma  + g * 4096;
#pragma unroll
    for (int it = 0; it < 8; ++it) {
      int j  = it * 512 + tid;      // j = k*512 + ci
      int k  = j >> 9;
      int ci = j & 511;
      float a = ab[j];
      float r = 1.0f / sb[j];
      sh.rs [ci * 8 + k] = r;
      sh.ars[ci * 8 + k] = a * r;
    }
  }
  if (tid < 8) sh.ssum[tid] = 0.0f;

  const int y0 = ((g >> 2) << 4) + (hh << 3);  // first image row of this half
  const int x0 = (g & 3) << 4;
  const float* xb = x + (size_t)b * NCH * 4096;

  float4 pf[8];  // register-staged next chunk (64 KB / 512 thr = 8 float4)
  auto prefetch = [&](int cc) {
#pragma unroll
    for (int it = 0; it < 8; ++it) {
      int idx   = it * 512 + tid;
      int q     = idx & 3;        // which float4 within the 16-px row
      int rowid = idx >> 2;       // 0..1023 = (channel, row-in-chunk)
      int ry    = rowid & 1;
      int ch    = rowid >> 1;
      pf[it] = *(const float4*)(xb + ((size_t)ch * 64 + (y0 + cc * 2 + ry)) * 64
                                + x0 + (q << 2));
    }
  };

  float S1[8];
#pragma unroll
  for (int k = 0; k < 8; ++k) S1[k] = 0.0f;

  __syncthreads();
  prefetch(0);

  const int p1p = tid >> 4;  // pass-1 pixel (0..31)
  const int p1c = tid & 15;  // pass-1 channel-group (0..15)

  for (int cc = 0; cc < 4; ++cc) {
    // ---- commit staged chunk to LDS [p][c]
#pragma unroll
    for (int it = 0; it < 8; ++it) {
      int idx   = it * 512 + tid;
      int q     = idx & 3;
      int rowid = idx >> 2;
      int ry    = rowid & 1;
      int ch    = rowid >> 1;
      int pb    = (ry << 4) + (q << 2);
      float4 v  = pf[it];
      sh.chunk[(pb + 0) * CHUNK_STRIDE + ch] = v.x;
      sh.chunk[(pb + 1) * CHUNK_STRIDE + ch] = v.y;
      sh.chunk[(pb + 2) * CHUNK_STRIDE + ch] = v.z;
      sh.chunk[(pb + 3) * CHUNK_STRIDE + ch] = v.w;
    }
    __syncthreads();

    // ---- pass 1: partial squared distances over 32 strided channels
    float sq[8];
#pragma unroll
    for (int k = 0; k < 8; ++k) sq[k] = 0.0f;
#pragma unroll
    for (int i = 0; i < 32; ++i) {
      int ci = p1c + (i << 4);
      float xv = sh.chunk[p1p * CHUNK_STRIDE + ci];
      float4 r0 = *(const float4*)&sh.rs [ci * 8];
      float4 r1 = *(const float4*)&sh.rs [ci * 8 + 4];
      float4 a0 = *(const float4*)&sh.ars[ci * 8];
      float4 a1 = *(const float4*)&sh.ars[ci * 8 + 4];
      float t;
      t = fmaf(xv, r0.x, -a0.x); sq[0] = fmaf(t, t, sq[0]);
      t = fmaf(xv, r0.y, -a0.y); sq[1] = fmaf(t, t, sq[1]);
      t = fmaf(xv, r0.z, -a0.z); sq[2] = fmaf(t, t, sq[2]);
      t = fmaf(xv, r0.w, -a0.w); sq[3] = fmaf(t, t, sq[3]);
      t = fmaf(xv, r1.x, -a1.x); sq[4] = fmaf(t, t, sq[4]);
      t = fmaf(xv, r1.y, -a1.y); sq[5] = fmaf(t, t, sq[5]);
      t = fmaf(xv, r1.z, -a1.z); sq[6] = fmaf(t, t, sq[6]);
      t = fmaf(xv, r1.w, -a1.w); sq[7] = fmaf(t, t, sq[7]);
    }
#pragma unroll
    for (int k = 0; k < 8; ++k) {
      sq[k] += __shfl_xor(sq[k], 1, 64);
      sq[k] += __shfl_xor(sq[k], 2, 64);
      sq[k] += __shfl_xor(sq[k], 4, 64);
      sq[k] += __shfl_xor(sq[k], 8, 64);
    }
    // softmax over the 8 nodes (all 16 lanes of a pixel group redundantly)
    float l[8];
#pragma unroll
    for (int k = 0; k < 8; ++k) l[k] = -0.5f * sq[k];
    float mx = l[0];
#pragma unroll
    for (int k = 1; k < 8; ++k) mx = fmaxf(mx, l[k]);
    float e[8], es = 0.0f;
#pragma unroll
    for (int k = 0; k < 8; ++k) { e[k] = __expf(l[k] - mx); es += e[k]; }
    float invs = 1.0f / es;
    if (p1c == 0) {
#pragma unroll
      for (int k = 0; k < 8; ++k) sh.soft[p1p * 8 + k] = e[k] * invs;
    }
    __syncthreads();

    if (cc < 3) prefetch(cc + 1);  // hide next chunk's HBM latency under pass 2

    // ---- pass 2: S1[k] += sum_p chunk[p][c] * soft[p][k]   (c = tid)
#pragma unroll
    for (int pp = 0; pp < 32; ++pp) {
      float xv = sh.chunk[pp * CHUNK_STRIDE + tid];
      float4 s0 = *(const float4*)&sh.soft[pp * 8];
      float4 s1 = *(const float4*)&sh.soft[pp * 8 + 4];
      S1[0] = fmaf(xv, s0.x, S1[0]);
      S1[1] = fmaf(xv, s0.y, S1[1]);
      S1[2] = fmaf(xv, s0.z, S1[2]);
      S1[3] = fmaf(xv, s0.w, S1[3]);
      S1[4] = fmaf(xv, s1.x, S1[4]);
      S1[5] = fmaf(xv, s1.y, S1[5]);
      S1[6] = fmaf(xv, s1.z, S1[6]);
      S1[7] = fmaf(xv, s1.w, S1[7]);
    }

    // ---- soft_assign output + per-k softsum partial
    if (tid < 256) {
      int k  = tid >> 5;
      int pp = tid & 31;
      float v = sh.soft[pp * 8 + k];
      soft_out[(((b << 7) + (g << 3) + k) << 8) + (hh << 7) + (cc << 5) + pp] = v;
      v += __shfl_xor(v, 1, 64);
      v += __shfl_xor(v, 2, 64);
      v += __shfl_xor(v, 4, 64);
      v += __shfl_xor(v, 8, 64);
      v += __shfl_xor(v, 16, 64);
      if (pp == 0) sh.ssum[k] += v;
    }
    __syncthreads();
  }

  // ---- epilogue: node partial = rs*S1 - ars*S0, accumulate to workspace
  const int node_base = (((b << 4) + g) << 3);
#pragma unroll
  for (int k = 0; k < 8; ++k) {
    float r   = sh.rs [tid * 8 + k];
    float ar  = sh.ars[tid * 8 + k];
    float acc = r * S1[k] - ar * sh.ssum[k];
    atomicAdd(&ws_nodes[(size_t)(node_base + k) * NCH + tid], acc);
  }
  if (tid < 8) atomicAdd(&ws_ssum[node_base + tid], sh.ssum[tid]);
}

__global__ __launch_bounds__(512, 2)
void gp_final(const float* __restrict__ ws_nodes,
              const float* __restrict__ ws_ssum,
              float* __restrict__ out) {  // nodes region of d_out
  const int bg  = blockIdx.x;     // b*16 + g
  const int b   = bg >> 4;
  const int g   = bg & 15;
  const int tid = threadIdx.x;    // = channel c
  __shared__ float red[8 * 8];    // [wave][k]
  __shared__ float sinv[8];
  __shared__ float invn[8];
  if (tid < 8) sinv[tid] = 1.0f / (ws_ssum[bg * 8 + tid] + 1e-9f);
  __syncthreads();
  const int wid  = tid >> 6;
  const int lane = tid & 63;
  float v[8];
#pragma unroll
  for (int k = 0; k < 8; ++k) {
    v[k] = ws_nodes[((size_t)bg * 8 + k) * NCH + tid] * sinv[k];
    float s = v[k] * v[k];
    s += __shfl_xor(s, 1, 64);
    s += __shfl_xor(s, 2, 64);
    s += __shfl_xor(s, 4, 64);
    s += __shfl_xor(s, 8, 64);
    s += __shfl_xor(s, 16, 64);
    s += __shfl_xor(s, 32, 64);
    if (lane == 0) red[wid * 8 + k] = s;
  }
  __syncthreads();
  if (tid < 8) {
    float t = 0.0f;
#pragma unroll
    for (int w = 0; w < 8; ++w) t += red[w * 8 + tid];
    invn[tid] = 1.0f / fmaxf(sqrtf(t), 1e-12f);
  }
  __syncthreads();
  float4 o0 = make_float4(v[0] * invn[0], v[1] * invn[1], v[2] * invn[2], v[3] * invn[3]);
  float4 o1 = make_float4(v[4] * invn[4], v[5] * invn[5], v[6] * invn[6], v[7] * invn[7]);
  float* dst = out + ((size_t)b * NCH + tid) * 128 + (g << 3);
  *(float4*)(dst)     = o0;
  *(float4*)(dst + 4) = o1;
}

extern "C" void kernel_launch(void* const* d_in, const int* in_sizes, int n_in,
                              void* d_out, int out_size, void* d_ws, size_t ws_size,
                              hipStream_t stream) {
  const float* x      = (const float*)d_in[0];
  const float* anchor = (const float*)d_in[1];
  const float* sigma  = (const float*)d_in[2];
  float* out = (float*)d_out;
  float* wsf = (float*)d_ws;

  // workspace: 128*8*512 node partials + 128*8 softsums
  const size_t n_nodes = 524288;           // 8*512*128 (also the nodes output size)
  const size_t ws_bytes = (n_nodes + 1024) * sizeof(float);
  hipMemsetAsync(d_ws, 0, ws_bytes, stream);

  float* ws_nodes = wsf;
  float* ws_ssum  = wsf + n_nodes;
  float* soft_out = out + n_nodes;         // soft_assign region

  gp_main <<<256, 512, 0, stream>>>(x, anchor, sigma, soft_out, ws_nodes, ws_ssum);
  gp_final<<<128, 512, 0, stream>>>(ws_nodes, ws_ssum, out);
}

// Round 2
// 41.054 us; speedup vs baseline: 4.1397x; 4.1397x over previous
//
#include <hip/hip_runtime.h>

// GraphProjection on MI355X (gfx950).
// x:(8,512,64,64) f32, anchor/sigma:(128,512) f32.
// d_out = nodes (8,512,128) ++ soft_assign (8,128,256).
//
// gp_main: wg = (b, g, row-part). Stages one 16-px row (512 ch) per chunk via
//   global_load_lds into a quad-swizzled [c][16] LDS tile, computes logits +
//   softmax (pass 1), accumulates S1[k][c] = sum_p x*soft (pass 2), stores raw
//   S1 partials to workspace with plain coalesced stores (NO atomics — device
//   atomics bypass XCD L2s and caused ~240MB of memory-side traffic last round).
// gp_final: S1 parts summed, S0 recomputed from soft_assign, node =
//   (rs*S1 - a*rs*S0)/(S0+1e-9), L2-normalized over C, transposed store.

#define NCH 512

typedef __attribute__((address_space(3))) void lds_void_t;
typedef const __attribute__((address_space(1))) void gbl_void_t;

__device__ __forceinline__ void gload_lds16(const float* g, float* l) {
  __builtin_amdgcn_global_load_lds((gbl_void_t*)g, (lds_void_t*)l, 16, 0, 0);
}

// LDS swizzles:
//  chunk[c][16 px]: pixel-quad qo stored at position qo ^ ((c>>1)&3)
//  anc  [c][16] = {rs[0..7], ars[0..7]}: float-quad f stored at f ^ ((c>>4)&3)
struct SharedMain {
  float anc[NCH * 16];        // 32 KB
  float chunk[NCH * 16];      // 32 KB
  float scratch[8 * 16 * 8];  // [wave][p][k]  4 KB
  float soft[16 * 8];         // [p][k]
};

__global__ __launch_bounds__(512, 4)
void gp_main(const float* __restrict__ x,
             const float* __restrict__ anchor,
             const float* __restrict__ sigma,
             float* __restrict__ soft_out,
             float* __restrict__ ws_s1,
             int parts_log2) {
  __shared__ SharedMain sh;
  const int tid = threadIdx.x;

  // XCD-aware swizzle: the 4 gx-siblings of a (b,part,gy) group share every
  // 128-B line of x -> pin them to the same XCD (assumes wg->XCD = bid%8).
  const int qb   = blockIdx.x;
  const int xcd  = qb & 7;
  const int slot = qb >> 3;
  const int gx   = slot & 3;
  const int Gp   = slot >> 2;
  const int G    = Gp * 8 + xcd;           // (b*parts+part)*4 + gy
  const int gy   = G & 3;
  const int tG   = G >> 2;
  const int parts = 1 << parts_log2;
  const int part  = tG & (parts - 1);
  const int b     = tG >> parts_log2;
  const int g     = gy * 4 + gx;
  const int nrows = 16 >> parts_log2;      // chunks per wg (1 row each)
  const int y0    = gy * 16 + part * nrows;
  const int x0    = gx * 16;
  const float* xb = x + (size_t)b * (NCH * 4096);

  // ---- anchors -> LDS: rs=1/sigma, ars=a/sigma, interleaved per channel
  {
    const float* ab = anchor + g * (8 * NCH);
    const float* sb = sigma  + g * (8 * NCH);
#pragma unroll
    for (int e = 0; e < 8; ++e) {
      int idx = e * 512 + tid;   // = k*512 + ci
      int k   = idx >> 9;
      int ci  = idx & 511;
      float a = ab[idx];
      float r = 1.0f / sb[idx];
      int sw  = (ci >> 4) & 3;
      int fq0 = (k >> 2) ^ sw;         // rs quad
      int fq1 = (2 + (k >> 2)) ^ sw;   // ars quad
      sh.anc[ci * 16 + (fq0 << 2) + (k & 3)] = r;
      sh.anc[ci * 16 + (fq1 << 2) + (k & 3)] = a * r;
    }
  }

  float S1[8];
#pragma unroll
  for (int k = 0; k < 8; ++k) S1[k] = 0.0f;

  const int cg   = tid >> 4;   // channel group 0..31 (16 ch each)
  const int p    = tid & 15;   // pixel within row
  const int wv   = tid >> 6;
  const int lane = tid & 63;
  const int asw  = cg & 3;     // anchor quad swizzle for this thread's channels

  for (int cc = 0; cc < nrows; ++cc) {
    const int y = y0 + cc;
    __syncthreads();  // previous pass 2 done -> chunk buffer reusable

    // ---- stage one row (512 ch x 16 px) direct to LDS, source pre-swizzled
#pragma unroll
    for (int it = 0; it < 4; ++it) {
      int flat = it * 512 + tid;        // 0..2047, LDS = chunk[flat*4..+3]
      int ci   = flat >> 2;
      int qd   = flat & 3;              // LDS quad position
      int qs   = qd ^ ((ci >> 1) & 3);  // original pixel quad fetched
      const float* src = xb + (size_t)ci * 4096 + y * 64 + x0 + (qs << 2);
      gload_lds16(src, &sh.chunk[flat << 2]);
    }
    asm volatile("s_waitcnt vmcnt(0)" ::: "memory");
    __syncthreads();  // chunk ready

    // ---- pass 1: squared distances, 16 channels per thread
    float sq[8];
#pragma unroll
    for (int k = 0; k < 8; ++k) sq[k] = 0.0f;
    {
      const float* ancb = sh.anc + cg * 256;
      const int pq = p >> 2, pr = p & 3;
#pragma unroll
      for (int i = 0; i < 16; ++i) {
        const float* ar = ancb + i * 16;
        float4 rlo = *(const float4*)(ar + ((0 ^ asw) << 2));
        float4 rhi = *(const float4*)(ar + ((1 ^ asw) << 2));
        float4 alo = *(const float4*)(ar + ((2 ^ asw) << 2));
        float4 ahi = *(const float4*)(ar + ((3 ^ asw) << 2));
        int ci = (cg << 4) + i;
        float xv = sh.chunk[(ci << 4) + ((pq ^ ((ci >> 1) & 3)) << 2) + pr];
        float t;
        t = fmaf(xv, rlo.x, -alo.x); sq[0] = fmaf(t, t, sq[0]);
        t = fmaf(xv, rlo.y, -alo.y); sq[1] = fmaf(t, t, sq[1]);
        t = fmaf(xv, rlo.z, -alo.z); sq[2] = fmaf(t, t, sq[2]);
        t = fmaf(xv, rlo.w, -alo.w); sq[3] = fmaf(t, t, sq[3]);
        t = fmaf(xv, rhi.x, -ahi.x); sq[4] = fmaf(t, t, sq[4]);
        t = fmaf(xv, rhi.y, -ahi.y); sq[5] = fmaf(t, t, sq[5]);
        t = fmaf(xv, rhi.z, -ahi.z); sq[6] = fmaf(t, t, sq[6]);
        t = fmaf(xv, rhi.w, -ahi.w); sq[7] = fmaf(t, t, sq[7]);
      }
    }
    // reduce over the wave's 4 channel-groups (lane bits 4,5)
#pragma unroll
    for (int k = 0; k < 8; ++k) {
      sq[k] += __shfl_xor(sq[k], 16, 64);
      sq[k] += __shfl_xor(sq[k], 32, 64);
    }
    if (lane < 16) {  // lane == p here
      *(float4*)&sh.scratch[((wv << 4) + lane) << 3]       =
          make_float4(sq[0], sq[1], sq[2], sq[3]);
      *(float4*)&sh.scratch[(((wv << 4) + lane) << 3) + 4] =
          make_float4(sq[4], sq[5], sq[6], sq[7]);
    }
    __syncthreads();

    // ---- cross-wave sum + softmax over 8 nodes (threads (p,k))
    if (tid < 128) {
      int pp = tid >> 3, k = tid & 7;
      float acc = 0.0f;
#pragma unroll
      for (int w = 0; w < 8; ++w) acc += sh.scratch[((w << 4) + pp) * 8 + k];
      float l = -0.5f * acc;
      float mx = l;
      mx = fmaxf(mx, __shfl_xor(mx, 1, 64));
      mx = fmaxf(mx, __shfl_xor(mx, 2, 64));
      mx = fmaxf(mx, __shfl_xor(mx, 4, 64));
      float e = __expf(l - mx);
      float es = e;
      es += __shfl_xor(es, 1, 64);
      es += __shfl_xor(es, 2, 64);
      es += __shfl_xor(es, 4, 64);
      sh.soft[(pp << 3) + k] = e / es;
    }
    __syncthreads();

    // ---- soft_assign out (coalesced 64-B per node row)
    if (tid < 128) {
      int k = tid >> 4, pp = tid & 15;
      soft_out[(size_t)((b << 7) + (g << 3) + k) * 256 +
               (part * nrows + cc) * 16 + pp] = sh.soft[(pp << 3) + k];
    }

    // ---- pass 2: S1[k] += sum_p chunk[c][p] * soft[p][k]   (c = tid)
    {
      const float* ch = sh.chunk + (tid << 4);
      const int csw = (tid >> 1) & 3;
#pragma unroll
      for (int qd = 0; qd < 4; ++qd) {
        float4 xv = *(const float4*)(ch + ((qd ^ csw) << 2));
#pragma unroll
        for (int j = 0; j < 4; ++j) {
          float xvj = (j == 0) ? xv.x : (j == 1) ? xv.y : (j == 2) ? xv.z : xv.w;
          const float* sp = &sh.soft[((qd << 2) + j) << 3];
          float4 s0 = *(const float4*)sp;
          float4 s1 = *(const float4*)(sp + 4);
          S1[0] = fmaf(xvj, s0.x, S1[0]);
          S1[1] = fmaf(xvj, s0.y, S1[1]);
          S1[2] = fmaf(xvj, s0.z, S1[2]);
          S1[3] = fmaf(xvj, s0.w, S1[3]);
          S1[4] = fmaf(xvj, s1.x, S1[4]);
          S1[5] = fmaf(xvj, s1.y, S1[5]);
          S1[6] = fmaf(xvj, s1.z, S1[6]);
          S1[7] = fmaf(xvj, s1.w, S1[7]);
        }
      }
    }
  }

  // ---- raw S1 partial to workspace (plain stores, written exactly once)
  const int bg = (b << 4) + g;
  float* wp = ws_s1 + ((size_t)(bg * parts + part) << 3) * NCH + tid;
#pragma unroll
  for (int k = 0; k < 8; ++k) wp[k * NCH] = S1[k];
}

__global__ __launch_bounds__(512, 4)
void gp_final(const float* __restrict__ anchor,
              const float* __restrict__ sigma,
              const float* __restrict__ soft_out,
              const float* __restrict__ ws_s1,
              float* __restrict__ nodes_out,
              int parts) {
  const int bg = blockIdx.x;   // b*16+g
  const int b  = bg >> 4, g = bg & 15;
  const int tid = threadIdx.x; // channel c
  __shared__ float sS0[8];
  __shared__ float red[8 * 8];
  __shared__ float invn[8];

  // S0[k] = sum over 256 px of soft_assign
  if (tid < 256) {
    int k = tid >> 5, sl = tid & 31;
    const float* sp = soft_out + (size_t)((b << 7) + (g << 3) + k) * 256 + (sl << 3);
    float4 a0 = *(const float4*)sp;
    float4 a1 = *(const float4*)(sp + 4);
    float v = a0.x + a0.y + a0.z + a0.w + a1.x + a1.y + a1.z + a1.w;
    v += __shfl_xor(v, 1, 64);
    v += __shfl_xor(v, 2, 64);
    v += __shfl_xor(v, 4, 64);
    v += __shfl_xor(v, 8, 64);
    v += __shfl_xor(v, 16, 64);
    if (sl == 0) sS0[k] = v;
  }
  __syncthreads();

  float S1[8];
#pragma unroll
  for (int k = 0; k < 8; ++k) S1[k] = 0.0f;
  for (int pt = 0; pt < parts; ++pt) {
    const float* wp = ws_s1 + ((size_t)(bg * parts + pt) << 3) * NCH + tid;
#pragma unroll
    for (int k = 0; k < 8; ++k) S1[k] += wp[k * NCH];
  }

  float v[8];
#pragma unroll
  for (int k = 0; k < 8; ++k) {
    float s  = sigma [((g << 3) + k) * NCH + tid];
    float a  = anchor[((g << 3) + k) * NCH + tid];
    float rs = 1.0f / s;
    float S0 = sS0[k];
    float nd = rs * S1[k] - (a * rs) * S0;
    v[k] = nd / (S0 + 1e-9f);
  }

  const int wv = tid >> 6, lane = tid & 63;
#pragma unroll
  for (int k = 0; k < 8; ++k) {
    float s = v[k] * v[k];
    s += __shfl_xor(s, 1, 64);
    s += __shfl_xor(s, 2, 64);
    s += __shfl_xor(s, 4, 64);
    s += __shfl_xor(s, 8, 64);
    s += __shfl_xor(s, 16, 64);
    s += __shfl_xor(s, 32, 64);
    if (lane == 0) red[(wv << 3) + k] = s;
  }
  __syncthreads();
  if (tid < 8) {
    float t2 = 0.0f;
#pragma unroll
    for (int w = 0; w < 8; ++w) t2 += red[(w << 3) + tid];
    invn[tid] = 1.0f / fmaxf(sqrtf(t2), 1e-12f);
  }
  __syncthreads();

  float4 o0 = make_float4(v[0] * invn[0], v[1] * invn[1], v[2] * invn[2], v[3] * invn[3]);
  float4 o1 = make_float4(v[4] * invn[4], v[5] * invn[5], v[6] * invn[6], v[7] * invn[7]);
  float* dst = nodes_out + ((size_t)(b * NCH) + tid) * 128 + (g << 3);
  *(float4*)(dst)     = o0;
  *(float4*)(dst + 4) = o1;
}

extern "C" void kernel_launch(void* const* d_in, const int* in_sizes, int n_in,
                              void* d_out, int out_size, void* d_ws, size_t ws_size,
                              hipStream_t stream) {
  const float* x      = (const float*)d_in[0];
  const float* anchor = (const float*)d_in[1];
  const float* sigma  = (const float*)d_in[2];
  float* out = (float*)d_out;
  float* wsf = (float*)d_ws;

  // ws need: 128 * parts * 8 * 512 * 4 B  (parts=4 -> 8 MB)
  int parts_log2;
  const size_t need4 = (size_t)128 * 4 * 8 * NCH * sizeof(float);
  if      (ws_size >= need4)     parts_log2 = 2;  // 512 wgs, 2 blocks/CU
  else if (ws_size >= need4 / 2) parts_log2 = 1;  // 256 wgs
  else                           parts_log2 = 0;  // 128 wgs (fallback)
  const int parts = 1 << parts_log2;

  float* soft_out = out + 524288;  // after nodes (8*512*128)

  gp_main <<<128 * parts, 512, 0, stream>>>(x, anchor, sigma, soft_out, wsf,
                                            parts_log2);
  gp_final<<<128, 512, 0, stream>>>(anchor, sigma, soft_out, wsf, out, parts);
}